// Round 4
// baseline (232.635 us; speedup 1.0000x reference)
//
#include <hip/hip_runtime.h>

static constexpr int H = 2048;
static constexpr int W = 2048;
static constexpr int BLOCK = 256;
static constexpr int PXT = 4;                             // pixels per thread
static constexpr int BLOCKS_PER_ROW = W / (BLOCK * PXT);  // 2
static constexpr int NBLOCKS = H * BLOCKS_PER_ROW;        // 4096

__device__ __forceinline__ float fexp2(float x){ return __builtin_amdgcn_exp2f(x); }
__device__ __forceinline__ float flog2(float x){ return __builtin_amdgcn_logf(x); }
__device__ __forceinline__ float frcp (float x){ return __builtin_amdgcn_rcpf(x); }

// Loads 6 values: cols x0-1 .. x0+4 of one row (zero outside the image).
__device__ __forceinline__ void load_row(const float* __restrict__ p, int b,
                                         bool hasL, bool hasR, float v[6]) {
    const float4 a = *(const float4*)(p + b);
    v[1] = a.x; v[2] = a.y; v[3] = a.z; v[4] = a.w;
    v[0] = hasL ? p[b - 1]   : 0.f;
    v[5] = hasR ? p[b + PXT] : 0.f;
}

// Per-pixel JS divergence over 3x3 Gaussian-weighted neighbor PDFs (sigma=1).
//   t = 0.5*log2(e)*d^2,  e = exp2(-t) = exp(-d^2/2)
//   per-pixel: pacc = Sp*invGp + Sq*invGq + log2 Gp + log2 Gq + 2*sum m*log2 m
//   (Sp = sum e*t); output = -ln2 * sum(pacc)
// __launch_bounds__(256, 3): VGPR cap 168 — round 3 showed the default
// heuristic caps at 60 VGPR (8 waves/EU) and spills ~60 floats to scratch,
// collapsing VALUBusy to 13%.
__global__ __launch_bounds__(BLOCK, 3) void jsd_kernel(
    const float* __restrict__ A, const float* __restrict__ B,
    float* __restrict__ partial, unsigned int* __restrict__ counter,
    float* __restrict__ out)
{
    constexpr float S   = 0.84932180028801905f;   // sqrt(0.5*log2(e))
    constexpr float LN2 = 0.69314718055994531f;

    const int bid  = blockIdx.x;
    const int y    = bid >> 1;                    // 2 blocks per row
    const int x0   = ((bid & 1) << 10) + (threadIdx.x << 2);
    const int base = y * W + x0;
    const bool hasL = (x0 > 0);
    const bool hasR = (x0 + PXT < W);

    float Av[3][6], Bv[3][6];
    load_row(A, base, hasL, hasR, Av[1]);
    load_row(B, base, hasL, hasR, Bv[1]);
    if (y > 0) {                                   // wave-uniform branch
        load_row(A, base - W, hasL, hasR, Av[0]);
        load_row(B, base - W, hasL, hasR, Bv[0]);
    } else {
        #pragma unroll
        for (int c = 0; c < 6; ++c) { Av[0][c] = 0.f; Bv[0][c] = 0.f; }
    }
    if (y < H - 1) {
        load_row(A, base + W, hasL, hasR, Av[2]);
        load_row(B, base + W, hasL, hasR, Bv[2]);
    } else {
        #pragma unroll
        for (int c = 0; c < 6; ++c) { Av[2][c] = 0.f; Bv[2][c] = 0.f; }
    }

    // horizontal pair exps (middle row), shared between adjacent pixels
    float heA[5], htA[5], heB[5], htB[5];          // e and e*t
    #pragma unroll
    for (int c = 0; c < 5; ++c) {
        float d, u, t, e;
        d = Av[1][c+1] - Av[1][c]; u = d*S; t = u*u; e = fexp2(-t);
        heA[c] = e; htA[c] = e*t;
        d = Bv[1][c+1] - Bv[1][c]; u = d*S; t = u*u; e = fexp2(-t);
        heB[c] = e; htB[c] = e*t;
    }

    float pacc = 0.f;
    #pragma unroll
    for (int j = 0; j < PXT; ++j) {
        const float ca = Av[1][j+1];
        const float cb = Bv[1][j+1];

        float Gp = 1.f + heA[j] + heA[j+1];
        float Sp = htA[j] + htA[j+1];
        float Gq = 1.f + heB[j] + heB[j+1];
        float Sq = htB[j] + htB[j+1];

        float veA[6], veB[6];
        #pragma unroll
        for (int r = 0; r < 2; ++r) {
            const int rr = r ? 2 : 0;
            #pragma unroll
            for (int c2 = 0; c2 < 3; ++c2) {
                float d, u, t, e;
                d = Av[rr][j+c2] - ca; u = d*S; t = u*u; e = fexp2(-t);
                veA[r*3+c2] = e; Gp += e; Sp = fmaf(e, t, Sp);
                d = Bv[rr][j+c2] - cb; u = d*S; t = u*u; e = fexp2(-t);
                veB[r*3+c2] = e; Gq += e; Sq = fmaf(e, t, Sq);
            }
        }

        const float ip = frcp(Gp), iq = frcp(Gq);
        const float hp = 0.5f*ip,  hq = 0.5f*iq;

        float m = hp + hq;                          // center tap (g=1 both)
        float mll = m * flog2(m);
        m = fmaf(heA[j],   hp, heB[j]  *hq); mll = fmaf(m, flog2(m), mll);
        m = fmaf(heA[j+1], hp, heB[j+1]*hq); mll = fmaf(m, flog2(m), mll);
        #pragma unroll
        for (int k = 0; k < 6; ++k) {
            m = fmaf(veA[k], hp, veB[k]*hq);
            mll = fmaf(m, flog2(m), mll);
        }

        pacc += fmaf(Sp, ip, Sq*iq) + flog2(Gp) + flog2(Gq) + 2.f*mll;
    }

    // wave64 reduce, cross-wave via LDS
    #pragma unroll
    for (int off = 32; off > 0; off >>= 1)
        pacc += __shfl_down(pacc, off, 64);

    __shared__ float wsum[BLOCK/64];
    __shared__ int isLast;
    const int lane = threadIdx.x & 63;
    const int wid  = threadIdx.x >> 6;
    if (lane == 0) wsum[wid] = pacc;
    __syncthreads();
    if (threadIdx.x == 0) {
        const float bsum = wsum[0] + wsum[1] + wsum[2] + wsum[3];
        __hip_atomic_store(&partial[blockIdx.x], bsum,
                           __ATOMIC_RELEASE, __HIP_MEMORY_SCOPE_AGENT);
        // acq_rel RMW: release publishes our partial; acquire (in the last
        // block) synchronizes with every prior release in the sequence.
        const unsigned old = __hip_atomic_fetch_add(counter, 1u,
                           __ATOMIC_ACQ_REL, __HIP_MEMORY_SCOPE_AGENT);
        isLast = (old == (unsigned)(NBLOCKS - 1));
    }
    __syncthreads();

    if (isLast) {   // block-uniform; fixed summation order => deterministic
        float s = 0.f;
        #pragma unroll
        for (int i = 0; i < NBLOCKS / BLOCK; ++i)
            s += __hip_atomic_load(&partial[i*BLOCK + threadIdx.x],
                                   __ATOMIC_RELAXED, __HIP_MEMORY_SCOPE_AGENT);
        #pragma unroll
        for (int off = 32; off > 0; off >>= 1)
            s += __shfl_down(s, off, 64);
        if (lane == 0) wsum[wid] = s;
        __syncthreads();
        if (threadIdx.x == 0)
            out[0] = -LN2 * (wsum[0] + wsum[1] + wsum[2] + wsum[3]);
    }
}

extern "C" void kernel_launch(void* const* d_in, const int* in_sizes, int n_in,
                              void* d_out, int out_size, void* d_ws, size_t ws_size,
                              hipStream_t stream) {
    const float* A = (const float*)d_in[0];
    const float* B = (const float*)d_in[1];
    float* out = (float*)d_out;
    float* partial = (float*)d_ws;                        // NBLOCKS floats
    unsigned int* counter = (unsigned int*)d_ws + NBLOCKS;

    hipMemsetAsync(counter, 0, sizeof(unsigned int), stream);
    jsd_kernel<<<NBLOCKS, BLOCK, 0, stream>>>(A, B, partial, counter, out);
}

// Round 5
// 28.461 us; speedup vs baseline: 8.1740x; 8.1740x over previous
//
#include <hip/hip_runtime.h>

static constexpr int H = 2048;
static constexpr int W = 2048;
static constexpr int BLOCK = 256;
static constexpr int PXT = 4;                             // pixels per thread
static constexpr int NBLOCKS = H * (W / (BLOCK * PXT));   // 4096
static constexpr int RBLOCK = 1024;

__device__ __forceinline__ float fexp2(float x){ return __builtin_amdgcn_exp2f(x); }
__device__ __forceinline__ float flog2(float x){ return __builtin_amdgcn_logf(x); }
__device__ __forceinline__ float frcp (float x){ return __builtin_amdgcn_rcpf(x); }

static constexpr float S_   = 0.84932180028801905f;   // sqrt(0.5*log2(e))
static constexpr float LN2_ = 0.69314718055994531f;

// One pixel's pacc contribution. ALL scalars — nothing the compiler can
// demote to scratch. u=d*S, t=u*u, e=exp2(-t)=exp(-d^2/2).
// pacc = Sp*ip + Sq*iq + log2 Gp + log2 Gq + 2*sum m*log2 m   (out = -ln2*sum)
__device__ __forceinline__ float pixel_term(
    // A: row-above l,c,r ; row-below l,c,r ; center
    float aul, float auc, float aur, float adl, float adc, float adr, float ca,
    // A: horizontal pair exps/e*t (left pair, right pair)
    float heAl, float heAr, float htAl, float htAr,
    // B: same
    float bul, float buc, float bur, float bdl, float bdc, float bdr, float cb,
    float heBl, float heBr, float htBl, float htBr)
{
    float Gp = 1.f + heAl + heAr;
    float Sp = htAl + htAr;
    float Gq = 1.f + heBl + heBr;
    float Sq = htBl + htBr;

    float d, t, e;
#define NB(nv, cv, G, Ssum, ev)                                   \
    d = (nv) - (cv); d *= S_; t = d * d; e = fexp2(-t);           \
    G += e; Ssum = fmaf(e, t, Ssum); const float ev = e;

    NB(aul, ca, Gp, Sp, veA0)  NB(auc, ca, Gp, Sp, veA1)  NB(aur, ca, Gp, Sp, veA2)
    NB(adl, ca, Gp, Sp, veA3)  NB(adc, ca, Gp, Sp, veA4)  NB(adr, ca, Gp, Sp, veA5)
    NB(bul, cb, Gq, Sq, veB0)  NB(buc, cb, Gq, Sq, veB1)  NB(bur, cb, Gq, Sq, veB2)
    NB(bdl, cb, Gq, Sq, veB3)  NB(bdc, cb, Gq, Sq, veB4)  NB(bdr, cb, Gq, Sq, veB5)
#undef NB

    const float ip = frcp(Gp), iq = frcp(Gq);
    const float hp = 0.5f * ip, hq = 0.5f * iq;

    float m = hp + hq;                       // center tap (g=1 for both)
    float mll = m * flog2(m);
#define MT(ea, eb)                                                \
    m = fmaf((ea), hp, (eb) * hq); mll = fmaf(m, flog2(m), mll);
    MT(heAl, heBl)  MT(heAr, heBr)
    MT(veA0, veB0)  MT(veA1, veB1)  MT(veA2, veB2)
    MT(veA3, veB3)  MT(veA4, veB4)  MT(veA5, veB5)
#undef MT

    return fmaf(Sp, ip, Sq * iq) + flog2(Gp) + flog2(Gq) + 2.f * mll;
}

__global__ __launch_bounds__(BLOCK, 4) void jsd_pixel_kernel(
    const float* __restrict__ A, const float* __restrict__ B,
    float* __restrict__ partial)
{
    const int bid  = blockIdx.x;
    const int y    = bid >> 1;                    // 2 blocks per row
    const int x0   = ((bid & 1) << 10) + (threadIdx.x << 2);
    const int base = y * W + x0;
    const bool hasL = (x0 > 0);
    const bool hasR = (x0 + PXT < W);

    // Safe (clamped) offsets for the rows above/below + zero masks.
    const int  offU = (y > 0)     ? base - W : base;
    const int  offD = (y < H - 1) ? base + W : base;
    const float mU  = (y > 0)     ? 1.f : 0.f;
    const float mD  = (y < H - 1) ? 1.f : 0.f;

    // Named row scalars: pfx0 = col x0-1, pfx1..4 = x0..x0+3, pfx5 = x0+4.
#define LOAD_ROW(p0,p1,p2,p3,p4,p5, ptr, off, msk)                \
    float p0,p1,p2,p3,p4,p5;                                      \
    { const float4 q_ = *(const float4*)((ptr) + (off));          \
      p1 = q_.x * (msk); p2 = q_.y * (msk);                       \
      p3 = q_.z * (msk); p4 = q_.w * (msk);                       \
      p0 = (hasL ? (ptr)[(off) - 1]   : 0.f) * (msk);             \
      p5 = (hasR ? (ptr)[(off) + PXT] : 0.f) * (msk); }

    LOAD_ROW(a10,a11,a12,a13,a14,a15, A, base, 1.f)   // A middle
    LOAD_ROW(b10,b11,b12,b13,b14,b15, B, base, 1.f)   // B middle
    LOAD_ROW(a00,a01,a02,a03,a04,a05, A, offU, mU)    // A above
    LOAD_ROW(b00,b01,b02,b03,b04,b05, B, offU, mU)
    LOAD_ROW(a20,a21,a22,a23,a24,a25, A, offD, mD)    // A below
    LOAD_ROW(b20,b21,b22,b23,b24,b25, B, offD, mD)
#undef LOAD_ROW

    // Horizontal pair exps for the middle row (shared between neighbors).
#define HP(he, ht, l, r)                                          \
    float he, ht;                                                 \
    { float d_ = (r) - (l); d_ *= S_; const float t_ = d_ * d_;   \
      he = fexp2(-t_); ht = he * t_; }
    HP(heA0, htA0, a10, a11)  HP(heA1, htA1, a11, a12)
    HP(heA2, htA2, a12, a13)  HP(heA3, htA3, a13, a14)
    HP(heA4, htA4, a14, a15)
    HP(heB0, htB0, b10, b11)  HP(heB1, htB1, b11, b12)
    HP(heB2, htB2, b12, b13)  HP(heB3, htB3, b13, b14)
    HP(heB4, htB4, b14, b15)
#undef HP

    float pacc;
    pacc  = pixel_term(a00,a01,a02, a20,a21,a22, a11, heA0,heA1, htA0,htA1,
                       b00,b01,b02, b20,b21,b22, b11, heB0,heB1, htB0,htB1);
    pacc += pixel_term(a01,a02,a03, a21,a22,a23, a12, heA1,heA2, htA1,htA2,
                       b01,b02,b03, b21,b22,b23, b12, heB1,heB2, htB1,htB2);
    pacc += pixel_term(a02,a03,a04, a22,a23,a24, a13, heA2,heA3, htA2,htA3,
                       b02,b03,b04, b22,b23,b24, b13, heB2,heB3, htB2,htB3);
    pacc += pixel_term(a03,a04,a05, a23,a24,a25, a14, heA3,heA4, htA3,htA4,
                       b03,b04,b05, b23,b24,b25, b14, heB3,heB4, htB3,htB4);

    // wave64 reduce, cross-wave via LDS
    #pragma unroll
    for (int off = 32; off > 0; off >>= 1)
        pacc += __shfl_down(pacc, off, 64);

    __shared__ float wsum[BLOCK / 64];
    const int lane = threadIdx.x & 63;
    const int wid  = threadIdx.x >> 6;
    if (lane == 0) wsum[wid] = pacc;
    __syncthreads();
    if (threadIdx.x == 0)
        partial[blockIdx.x] = wsum[0] + wsum[1] + wsum[2] + wsum[3];
}

// Deterministic final reduce of NBLOCKS partials (single block, 16 waves).
__global__ __launch_bounds__(RBLOCK) void jsd_final_reduce(
    const float* __restrict__ partial, float* __restrict__ out)
{
    float s = 0.f;
    #pragma unroll
    for (int i = 0; i < NBLOCKS / RBLOCK; ++i)
        s += partial[i * RBLOCK + threadIdx.x];

    #pragma unroll
    for (int off = 32; off > 0; off >>= 1)
        s += __shfl_down(s, off, 64);

    __shared__ float wsum[RBLOCK / 64];
    const int lane = threadIdx.x & 63;
    const int wid  = threadIdx.x >> 6;
    if (lane == 0) wsum[wid] = s;
    __syncthreads();
    if (threadIdx.x == 0) {
        float t = 0.f;
        #pragma unroll
        for (int i = 0; i < RBLOCK / 64; ++i) t += wsum[i];
        out[0] = -LN2_ * t;
    }
}

extern "C" void kernel_launch(void* const* d_in, const int* in_sizes, int n_in,
                              void* d_out, int out_size, void* d_ws, size_t ws_size,
                              hipStream_t stream) {
    const float* A = (const float*)d_in[0];
    const float* B = (const float*)d_in[1];
    float* out = (float*)d_out;
    float* partial = (float*)d_ws;    // NBLOCKS floats = 16 KiB

    jsd_pixel_kernel<<<NBLOCKS, BLOCK, 0, stream>>>(A, B, partial);
    jsd_final_reduce<<<1, RBLOCK, 0, stream>>>(partial, out);
}